// Round 7
// baseline (49.773 us; speedup 1.0000x reference)
//
#include <hip/hip_runtime.h>
#include <stdint.h>

#define NROWS 8192
#define NDIM 128
#define NBLK 512                    // total blocks; 0..99 class, 100 g-reduce, 101.. exit
#define ROWS_PER_BLK (NROWS / NBLK) // 16
#define NCLS 100
#define LCAP 512                    // per-class list capacity (n_c ~ 82 +- 9)

typedef short s16x8 __attribute__((ext_vector_type(8)));
typedef float f32x4 __attribute__((ext_vector_type(4)));
typedef __attribute__((address_space(3))) uint32_t lds_u32_t;
typedef __attribute__((address_space(1))) const uint32_t glb_u32_t;

// ws byte offsets
#define WS_FHAT  0u         // 8192*128 bf16 = 2 MB
#define WS_PG    0x200000u  // 512 x 128 f32 partial g (256 KB)
#define WS_PA    0x240000u  // 512 f32 partial anchor sums
#define WS_LIST  0x241000u  // 100 x 512 int class row lists (200 KB)
#define WS_SLOT  0x274000u  // 100 float4 {prelu, spos, n, pad}
#define WS_META  0x274800u  // [1]=||g||^2, [2]=sum anchors
#define WS_SYNC  0x274840u  // [0]=phase barrier ctr, [1]=election ctr (memset 0)

__device__ __forceinline__ uint32_t f32_to_bf16_rne(float x) {
    uint32_t u = __float_as_uint(x);
    return (u + 0x7FFFu + ((u >> 16) & 1u)) >> 16;
}

__device__ __forceinline__ float agent_load_f(const float* p) {
    return __hip_atomic_load(p, __ATOMIC_RELAXED, __HIP_MEMORY_SCOPE_AGENT);
}

__global__ __launch_bounds__(256) void fused_loss(const float* __restrict__ feat,
                                                  const int* __restrict__ labels,
                                                  char* __restrict__ ws,
                                                  float* __restrict__ out) {
    __shared__ __align__(16) char sm[65536];  // tiles / reduce scratch
    __shared__ int lcnt, win;
    int tid = threadIdx.x;
    int lane = tid & 63, wave = tid >> 6;
    int b = blockIdx.x;
    int* bar   = (int*)(ws + WS_SYNC);
    int* elect = (int*)(ws + WS_SYNC) + 1;

    // ---- phase 1: normalize 16 rows (ALL 512 blocks; R5-k1 verbatim) ----
    {
        const float2* fp = (const float2*)feat;
        uint32_t* fhat = (uint32_t*)(ws + WS_FHAT);
        float gx = 0.f, gy = 0.f, aacc = 0.f;
        int rbase = b * ROWS_PER_BLK;
#pragma unroll
        for (int k = 0; k < ROWS_PER_BLK / 4; ++k) {
            int row = rbase + k * 4 + wave;
            float2 v = fp[row * 64 + lane];
            float ss = v.x * v.x + v.y * v.y;
#pragma unroll
            for (int o = 32; o; o >>= 1) ss += __shfl_xor(ss, o);
            float sc = 1.0f / fmaxf(sqrtf(ss), 1e-12f);
            float fx = v.x * sc, fy = v.y * sc;
            gx += fx; gy += fy;
            aacc += ss * sc * sc;  // ||f_hat||^2 (anchor)
            fhat[row * 64 + lane] = (f32_to_bf16_rne(fy) << 16) | f32_to_bf16_rne(fx);
        }
        float (*gbuf)[128] = (float(*)[128])sm;
        float* abuf = (float*)(sm + 2048);
        gbuf[wave][lane * 2] = gx;
        gbuf[wave][lane * 2 + 1] = gy;
        if (lane == 0) abuf[wave] = aacc;
        __syncthreads();
        float* pg = (float*)(ws + WS_PG) + b * NDIM;
        if (wave == 0) {
            float s0 = gbuf[0][lane*2]   + gbuf[1][lane*2]   + gbuf[2][lane*2]   + gbuf[3][lane*2];
            float s1 = gbuf[0][lane*2+1] + gbuf[1][lane*2+1] + gbuf[2][lane*2+1] + gbuf[3][lane*2+1];
            ((float2*)pg)[lane] = float2{s0, s1};
        }
        if (tid == 0) ((float*)(ws + WS_PA))[b] = abuf[0] + abuf[1] + abuf[2] + abuf[3];
    }
    // arrive: syncthreads drains all waves' stores; tid0 fences + releases
    __syncthreads();
    if (tid == 0) {
        __threadfence();
        __hip_atomic_fetch_add(bar, 1, __ATOMIC_RELEASE, __HIP_MEMORY_SCOPE_AGENT);
    }
    if (b > NCLS) return;   // 411 blocks free their CU slots -> spinners can't starve workers

    // ---- overlap with normalize tail: class blocks build their row list ----
    int shl = 0;
    if (b < NCLS) {
        if (tid == 0) lcnt = 0;
        // int64-label detect: values 0..99 -> all odd int32 words zero
        unsigned long long bl = __ballot(labels[2 * lane + 1] != 0);
        shl = (bl == 0ull) ? 1 : 0;
        __syncthreads();
        int* list = (int*)(ws + WS_LIST) + b * LCAP;
        int labv[32];
#pragma unroll
        for (int r = 0; r < 32; ++r) labv[r] = labels[(r * 256 + tid) << shl];
#pragma unroll
        for (int r = 0; r < 32; ++r) {
            if (labv[r] == b) {
                int p = atomicAdd(&lcnt, 1);
                if (p < LCAP) list[p] = r * 256 + tid;
            }
        }
        __syncthreads();   // list stores drained (own-block RAW is L1/L2 coherent)
    }

    // ---- spin until all 512 blocks finished phase 1 ----
    if (tid == 0) {
        while (__hip_atomic_load(bar, __ATOMIC_ACQUIRE, __HIP_MEMORY_SCOPE_AGENT) < NBLK)
            __builtin_amdgcn_s_sleep(2);
    }
    __syncthreads();

    if (b == NCLS) {
        // ---- g-reduce: ||g||^2 and sum anchors (R5-k2 block-100 verbatim) ----
        const float* pg = (const float*)(ws + WS_PG);
        const float* pa = (const float*)(ws + WS_PA);
        int dim = tid & 127, half = tid >> 7;
        float acc = 0.f;
#pragma unroll 16
        for (int bb = half * 256; bb < half * 256 + 256; ++bb) acc += pg[bb * NDIM + dim];
        float* l = (float*)sm;
        l[half * 128 + dim] = acc;
        float av = pa[tid] + pa[tid + 256];
#pragma unroll
        for (int o = 32; o; o >>= 1) av += __shfl_xor(av, o);
        __syncthreads();
        float sq = 0.f;
        if (half == 0) { float tot = l[dim] + l[128 + dim]; sq = tot * tot; }
#pragma unroll
        for (int o = 32; o; o >>= 1) sq += __shfl_xor(sq, o);
        float* r2 = (float*)sm + 256;
        if (lane == 0) { r2[wave * 2] = sq; r2[wave * 2 + 1] = av; }
        __syncthreads();
        if (tid == 0) {
            float* meta = (float*)(ws + WS_META);
            meta[1] = r2[0] + r2[2] + r2[4] + r2[6];
            meta[2] = r2[1] + r2[3] + r2[5] + r2[7];
        }
    } else {
        // ---- class block: stage gathered fhat rows -> MFMA -> fused epilogue ----
        int c = b;
        int nfull = lcnt;
        int n = nfull > LCAP ? LCAP : nfull;
        int* list = (int*)(ws + WS_LIST) + c * LCAP;
        const char* fhat = ws + WS_FHAT;
        int wm = wave >> 1, wn = wave & 1;
        float prelu = 0.f, spos = 0.f;
        int ntiles = (n + 127) >> 7;
        int r16 = tid >> 4;
        uint32_t cst = (uint32_t)((tid & 15) << 4);
        for (int ti = 0; ti < ntiles; ++ti)
            for (int tj = 0; tj <= ti; ++tj) {   // symmetric: lower-tri tile pairs only
                int rows_a = n - ti * 128; if (rows_a > 128) rows_a = 128;
                int rows_b = n - tj * 128; if (rows_b > 128) rows_b = 128;
                int slabs_a = (rows_a + 15) >> 4;
                int slabs_b = (rows_b + 15) >> 4;
                bool same = (ti == tj);
                __syncthreads();
                // stage: linear LDS dest, inverse-swizzled per-lane global src
#pragma unroll
                for (int it = 0; it < 8; ++it) {
                    if (it < slabs_a) {
                        int row = it * 16 + r16;
                        uint32_t csrc = cst ^ (uint32_t)((row & 7) << 4);
                        int pa_ = ti * 128 + row;
                        int ra = list[(pa_ < n) ? pa_ : 0];
                        __builtin_amdgcn_global_load_lds(
                            (glb_u32_t*)(fhat + ra * 256 + csrc),
                            (lds_u32_t*)(sm + it * 4096 + tid * 16), 16, 0, 0);
                    }
                }
                if (!same) {
#pragma unroll
                    for (int it = 0; it < 8; ++it) {
                        if (it < slabs_b) {
                            int row = it * 16 + r16;
                            uint32_t csrc = cst ^ (uint32_t)((row & 7) << 4);
                            int pb_ = tj * 128 + row;
                            int rb = list[(pb_ < n) ? pb_ : 0];
                            __builtin_amdgcn_global_load_lds(
                                (glb_u32_t*)(fhat + rb * 256 + csrc),
                                (lds_u32_t*)(sm + 32768 + it * 4096 + tid * 16), 16, 0, 0);
                        }
                    }
                }
                __syncthreads();
                const char* bbase = same ? sm : (sm + 32768);
                int rb_ = lane & 15;
                uint32_t kcol = (uint32_t)((lane >> 4) << 4);
                f32x4 acc[4][4];
#pragma unroll
                for (int mi = 0; mi < 4; ++mi)
#pragma unroll
                    for (int ni = 0; ni < 4; ++ni) acc[mi][ni] = f32x4{0.f, 0.f, 0.f, 0.f};
#pragma unroll
                for (int ks = 0; ks < 4; ++ks) {
                    uint32_t c2 = (uint32_t)(ks * 64) + kcol;
                    s16x8 a[4], bfr[4];
#pragma unroll
                    for (int mi = 0; mi < 4; ++mi) {
                        int r = wm * 64 + mi * 16 + rb_;
                        uint32_t ad = (uint32_t)(r * 256) + (c2 ^ (uint32_t)((r & 7) << 4));
                        a[mi] = *reinterpret_cast<const s16x8*>(sm + ad);
                    }
#pragma unroll
                    for (int ni = 0; ni < 4; ++ni) {
                        int r = wn * 64 + ni * 16 + rb_;
                        uint32_t ad = (uint32_t)(r * 256) + (c2 ^ (uint32_t)((r & 7) << 4));
                        bfr[ni] = *reinterpret_cast<const s16x8*>(bbase + ad);
                    }
#pragma unroll
                    for (int mi = 0; mi < 4; ++mi)
#pragma unroll
                        for (int ni = 0; ni < 4; ++ni)
                            acc[mi][ni] = __builtin_amdgcn_mfma_f32_16x16x32_bf16(
                                a[mi], bfr[ni], acc[mi][ni], 0, 0, 0);
                }
                float tw = same ? 1.f : 2.f;   // off-diagonal tile pairs count twice
#pragma unroll
                for (int ni = 0; ni < 4; ++ni) {
                    int jp = tj * 128 + wn * 64 + ni * 16 + rb_;
#pragma unroll
                    for (int mi = 0; mi < 4; ++mi)
#pragma unroll
                        for (int rr = 0; rr < 4; ++rr) {
                            int ip = ti * 128 + wm * 64 + mi * 16 + ((lane >> 4) << 2) + rr;
                            bool vld = (ip < n) && (jp < n) && (ip != jp);
                            float s = acc[mi][ni][rr];
                            prelu += vld ? tw * fmaxf(fmaf(10.f, s, -9.f), 0.f) : 0.f;
                            spos  += vld ? tw * s : 0.f;
                        }
                }
            }
#pragma unroll
        for (int o = 32; o; o >>= 1) { prelu += __shfl_xor(prelu, o); spos += __shfl_xor(spos, o); }
        __syncthreads();   // tiles dead; reuse sm for block reduce
        float* rs = (float*)sm;
        if (lane == 0) { rs[wave * 2] = prelu; rs[wave * 2 + 1] = spos; }
        __syncthreads();
        if (tid == 0) {
            float4* slot = (float4*)(ws + WS_SLOT);
            slot[c] = float4{rs[0] + rs[2] + rs[4] + rs[6],
                             rs[1] + rs[3] + rs[5] + rs[7],
                             (float)nfull, 0.f};
        }
    }

    // ---- last-arriving of the 101 worker blocks computes the final scalar ----
    if (tid == 0) {
        __threadfence();
        int old = __hip_atomic_fetch_add(elect, 1, __ATOMIC_ACQ_REL, __HIP_MEMORY_SCOPE_AGENT);
        win = (old == NCLS);  // 101 workers -> last sees old == 100
    }
    __syncthreads();
    if (win && tid < 64) {
        const float* slot = (const float*)(ws + WS_SLOT);
        float pr = 0.f, sp = 0.f, sn2 = 0.f;
        for (int i = tid; i < NCLS; i += 64) {
            pr += agent_load_f(&slot[4 * i]);
            sp += agent_load_f(&slot[4 * i + 1]);
            float nc = agent_load_f(&slot[4 * i + 2]);
            sn2 += nc * nc;
        }
#pragma unroll
        for (int o = 32; o; o >>= 1) {
            pr += __shfl_xor(pr, o); sp += __shfl_xor(sp, o); sn2 += __shfl_xor(sn2, o);
        }
        if (tid == 0) {
            const float* meta = (const float*)(ws + WS_META);
            double g2 = (double)agent_load_f(&meta[1]);
            double sa = (double)agent_load_f(&meta[2]);
            double count = 8192.0 * 8191.0;
            double nposoff = (double)sn2 - 8192.0;
            double nneg = count - nposoff;
            double sall = g2 - sa;                 // sum_{i != j} s_ij
            double sneg = sall - (double)sp;
            double loss = ((double)pr + 11.0 * nneg - 10.0 * sneg) / count;
            out[0] = (float)loss;
        }
    }
}

extern "C" void kernel_launch(void* const* d_in, const int* in_sizes, int n_in,
                              void* d_out, int out_size, void* d_ws, size_t ws_size,
                              hipStream_t stream) {
    const float* feat = (const float*)d_in[0];
    const int* labels = (const int*)d_in[1];
    float* out = (float*)d_out;
    char* ws = (char*)d_ws;

    hipMemsetAsync(ws + WS_SYNC, 0, 8, stream);   // zero barrier + election counters
    fused_loss<<<NBLK, 256, 0, stream>>>(feat, labels, ws, out);
}

// Round 8
// 21.805 us; speedup vs baseline: 2.2827x; 2.2827x over previous
//
#include <hip/hip_runtime.h>
#include <stdint.h>

#define NROWS 8192
#define NDIM 128
#define NCLS 100
#define NBK1 512                    // normalize blocks in k1 (16 rows each)
#define ROWS_PER_BLK (NROWS / NBK1) // 16
#define LCAP 512                    // per-class list capacity (n_c ~ 82 +- 9)

typedef short s16x8 __attribute__((ext_vector_type(8)));
typedef float f32x4 __attribute__((ext_vector_type(4)));
typedef __attribute__((address_space(3))) uint32_t lds_u32_t;
typedef __attribute__((address_space(1))) const uint32_t glb_u32_t;

// ws byte offsets
#define WS_FHAT  0u         // 8192*128 bf16 = 2 MB
#define WS_PG    0x200000u  // 512 x 128 f32 partial g (256 KB)
#define WS_PA    0x240000u  // 512 f32 partial anchor sums
#define WS_LIST  0x241000u  // 100 x 512 int class row lists (200 KB)
#define WS_LCNT  0x274000u  // 100 int class counts
#define WS_SLOT  0x275000u  // 100 float4 {prelu, spos, n, pad}
#define WS_META  0x275800u  // [1]=||g||^2, [2]=sum anchors
#define WS_DONE  0x275840u  // k2 election counter

__device__ __forceinline__ uint32_t f32_to_bf16_rne(float x) {
    uint32_t u = __float_as_uint(x);
    return (u + 0x7FFFu + ((u >> 16) & 1u)) >> 16;
}

__device__ __forceinline__ float agent_load_f(const float* p) {
    return __hip_atomic_load(p, __ATOMIC_RELAXED, __HIP_MEMORY_SCOPE_AGENT);
}

// Blocks 0..99: build class b's row list (independent of normalize output).
// Blocks 100..611: normalize 16 rows each -> fhat (bf16), partial g, partial anchor.
__global__ __launch_bounds__(256) void k1_normalize_scan(const float* __restrict__ feat,
                                                         const int* __restrict__ labels,
                                                         char* __restrict__ ws) {
    int tid = threadIdx.x;
    int wave = tid >> 6, lane = tid & 63;

    if (blockIdx.x < NCLS) {
        // ---- list builder for class b ----
        __shared__ int lcnt;
        int b = blockIdx.x;
        if (tid == 0) {
            lcnt = 0;
            if (b == 0) *(int*)(ws + WS_DONE) = 0;   // reset k2 election counter
        }
        // int64-label detect: values 0..99 -> all odd int32 words zero
        unsigned long long bl = __ballot(labels[2 * lane + 1] != 0);
        int shl = (bl == 0ull) ? 1 : 0;
        __syncthreads();
        int* list = (int*)(ws + WS_LIST) + b * LCAP;
        int labv[32];
#pragma unroll
        for (int r = 0; r < 32; ++r) labv[r] = labels[(r * 256 + tid) << shl];
#pragma unroll
        for (int r = 0; r < 32; ++r) {
            if (labv[r] == b) {
                int p = atomicAdd(&lcnt, 1);
                if (p < LCAP) list[p] = r * 256 + tid;
            }
        }
        __syncthreads();
        if (tid == 0) ((int*)(ws + WS_LCNT))[b] = lcnt;
        return;
    }

    // ---- normalize 16 rows (R5-k1 verbatim) ----
    int nb = blockIdx.x - NCLS;
    const float2* fp = (const float2*)feat;
    uint32_t* fhat = (uint32_t*)(ws + WS_FHAT);
    float gx = 0.f, gy = 0.f, aacc = 0.f;
    int rbase = nb * ROWS_PER_BLK;
#pragma unroll
    for (int k = 0; k < ROWS_PER_BLK / 4; ++k) {
        int row = rbase + k * 4 + wave;
        float2 v = fp[row * 64 + lane];
        float ss = v.x * v.x + v.y * v.y;
#pragma unroll
        for (int o = 32; o; o >>= 1) ss += __shfl_xor(ss, o);
        float sc = 1.0f / fmaxf(sqrtf(ss), 1e-12f);
        float fx = v.x * sc, fy = v.y * sc;
        gx += fx; gy += fy;
        aacc += ss * sc * sc;  // ||f_hat||^2 (anchor)
        fhat[row * 64 + lane] = (f32_to_bf16_rne(fy) << 16) | f32_to_bf16_rne(fx);
    }
    __shared__ float gbuf[4][128];
    __shared__ float abuf[4];
    gbuf[wave][lane * 2] = gx;
    gbuf[wave][lane * 2 + 1] = gy;
    if (lane == 0) abuf[wave] = aacc;
    __syncthreads();
    float* pg = (float*)(ws + WS_PG) + nb * NDIM;
    if (wave == 0) {
        float s0 = gbuf[0][lane*2]   + gbuf[1][lane*2]   + gbuf[2][lane*2]   + gbuf[3][lane*2];
        float s1 = gbuf[0][lane*2+1] + gbuf[1][lane*2+1] + gbuf[2][lane*2+1] + gbuf[3][lane*2+1];
        ((float2*)pg)[lane] = float2{s0, s1};
    }
    if (tid == 0) ((float*)(ws + WS_PA))[nb] = abuf[0] + abuf[1] + abuf[2] + abuf[3];
}

// Blocks 0..99: within-class pairwise MFMA (list prebuilt by k1).
// Block 100: reduce partial g -> ||g||^2 and partial anchors -> meta.
// Last-arriving block computes the final loss scalar.
__global__ __launch_bounds__(256) void k2_classes(char* __restrict__ ws,
                                                  float* __restrict__ out) {
    __shared__ __align__(16) char sm[65536];  // A tile [0,32K), B tile [32K,64K)
    __shared__ int win;
    int tid = threadIdx.x;
    int lane = tid & 63, wave = tid >> 6;

    if (blockIdx.x == NCLS) {
        const float* pg = (const float*)(ws + WS_PG);
        const float* pa = (const float*)(ws + WS_PA);
        int dim = tid & 127, half = tid >> 7;
        float acc = 0.f;
#pragma unroll 16
        for (int b = half * 256; b < half * 256 + 256; ++b) acc += pg[b * NDIM + dim];
        float* l = (float*)sm;
        l[half * 128 + dim] = acc;
        float av = pa[tid] + pa[tid + 256];
#pragma unroll
        for (int o = 32; o; o >>= 1) av += __shfl_xor(av, o);
        __syncthreads();
        float sq = 0.f;
        if (half == 0) { float tot = l[dim] + l[128 + dim]; sq = tot * tot; }
#pragma unroll
        for (int o = 32; o; o >>= 1) sq += __shfl_xor(sq, o);
        float* r2 = (float*)sm + 256;
        if (lane == 0) { r2[wave * 2] = sq; r2[wave * 2 + 1] = av; }
        __syncthreads();
        if (tid == 0) {
            float* meta = (float*)(ws + WS_META);
            meta[1] = r2[0] + r2[2] + r2[4] + r2[6];
            meta[2] = r2[1] + r2[3] + r2[5] + r2[7];
        }
    } else {
        int c = blockIdx.x;
        int nfull = ((const int*)(ws + WS_LCNT))[c];
        int n = nfull > LCAP ? LCAP : nfull;
        const int* list = (const int*)(ws + WS_LIST) + c * LCAP;
        const char* fhat = ws + WS_FHAT;
        int wm = wave >> 1, wn = wave & 1;
        float prelu = 0.f, spos = 0.f;
        int ntiles = (n + 127) >> 7;
        int r16 = tid >> 4;
        uint32_t cst = (uint32_t)((tid & 15) << 4);
        for (int ti = 0; ti < ntiles; ++ti)
            for (int tj = 0; tj <= ti; ++tj) {   // symmetric: lower-tri tile pairs only
                int rows_a = n - ti * 128; if (rows_a > 128) rows_a = 128;
                int rows_b = n - tj * 128; if (rows_b > 128) rows_b = 128;
                int slabs_a = (rows_a + 15) >> 4;
                int slabs_b = (rows_b + 15) >> 4;
                bool same = (ti == tj);
                __syncthreads();
                // stage: linear LDS dest, inverse-swizzled per-lane global src
#pragma unroll
                for (int it = 0; it < 8; ++it) {
                    if (it < slabs_a) {
                        int row = it * 16 + r16;
                        uint32_t csrc = cst ^ (uint32_t)((row & 7) << 4);
                        int pa_ = ti * 128 + row;
                        int ra = list[(pa_ < n) ? pa_ : 0];
                        __builtin_amdgcn_global_load_lds(
                            (glb_u32_t*)(fhat + ra * 256 + csrc),
                            (lds_u32_t*)(sm + it * 4096 + tid * 16), 16, 0, 0);
                    }
                }
                if (!same) {
#pragma unroll
                    for (int it = 0; it < 8; ++it) {
                        if (it < slabs_b) {
                            int row = it * 16 + r16;
                            uint32_t csrc = cst ^ (uint32_t)((row & 7) << 4);
                            int pb_ = tj * 128 + row;
                            int rb = list[(pb_ < n) ? pb_ : 0];
                            __builtin_amdgcn_global_load_lds(
                                (glb_u32_t*)(fhat + rb * 256 + csrc),
                                (lds_u32_t*)(sm + 32768 + it * 4096 + tid * 16), 16, 0, 0);
                        }
                    }
                }
                __syncthreads();
                const char* bbase = same ? sm : (sm + 32768);
                int rb_ = lane & 15;
                uint32_t kcol = (uint32_t)((lane >> 4) << 4);
                f32x4 acc[4][4];
#pragma unroll
                for (int mi = 0; mi < 4; ++mi)
#pragma unroll
                    for (int ni = 0; ni < 4; ++ni) acc[mi][ni] = f32x4{0.f, 0.f, 0.f, 0.f};
#pragma unroll
                for (int ks = 0; ks < 4; ++ks) {
                    uint32_t c2 = (uint32_t)(ks * 64) + kcol;
                    s16x8 a[4], bfr[4];
#pragma unroll
                    for (int mi = 0; mi < 4; ++mi) {
                        int r = wm * 64 + mi * 16 + rb_;
                        uint32_t ad = (uint32_t)(r * 256) + (c2 ^ (uint32_t)((r & 7) << 4));
                        a[mi] = *reinterpret_cast<const s16x8*>(sm + ad);
                    }
#pragma unroll
                    for (int ni = 0; ni < 4; ++ni) {
                        int r = wn * 64 + ni * 16 + rb_;
                        uint32_t ad = (uint32_t)(r * 256) + (c2 ^ (uint32_t)((r & 7) << 4));
                        bfr[ni] = *reinterpret_cast<const s16x8*>(bbase + ad);
                    }
#pragma unroll
                    for (int mi = 0; mi < 4; ++mi)
#pragma unroll
                        for (int ni = 0; ni < 4; ++ni)
                            acc[mi][ni] = __builtin_amdgcn_mfma_f32_16x16x32_bf16(
                                a[mi], bfr[ni], acc[mi][ni], 0, 0, 0);
                }
                float tw = same ? 1.f : 2.f;   // off-diagonal tile pairs count twice
#pragma unroll
                for (int ni = 0; ni < 4; ++ni) {
                    int jp = tj * 128 + wn * 64 + ni * 16 + rb_;
#pragma unroll
                    for (int mi = 0; mi < 4; ++mi)
#pragma unroll
                        for (int rr = 0; rr < 4; ++rr) {
                            int ip = ti * 128 + wm * 64 + mi * 16 + ((lane >> 4) << 2) + rr;
                            bool vld = (ip < n) && (jp < n) && (ip != jp);
                            float s = acc[mi][ni][rr];
                            prelu += vld ? tw * fmaxf(fmaf(10.f, s, -9.f), 0.f) : 0.f;
                            spos  += vld ? tw * s : 0.f;
                        }
                }
            }
#pragma unroll
        for (int o = 32; o; o >>= 1) { prelu += __shfl_xor(prelu, o); spos += __shfl_xor(spos, o); }
        __syncthreads();   // tiles dead; reuse sm for the block reduce
        float* rs = (float*)sm;
        if (lane == 0) { rs[wave * 2] = prelu; rs[wave * 2 + 1] = spos; }
        __syncthreads();
        if (tid == 0) {
            float4* slot = (float4*)(ws + WS_SLOT);
            slot[c] = float4{rs[0] + rs[2] + rs[4] + rs[6],
                             rs[1] + rs[3] + rs[5] + rs[7],
                             (float)nfull, 0.f};
        }
    }

    // ---- last-arriving block computes the final scalar ----
    if (tid == 0) {
        __threadfence();
        int old = __hip_atomic_fetch_add((int*)(ws + WS_DONE), 1,
                                         __ATOMIC_ACQ_REL, __HIP_MEMORY_SCOPE_AGENT);
        win = (old == NCLS);  // 101 blocks -> last sees old == 100
    }
    __syncthreads();
    if (win && tid < 64) {
        const float* slot = (const float*)(ws + WS_SLOT);
        float pr = 0.f, sp = 0.f, sn2 = 0.f;
        for (int i = tid; i < NCLS; i += 64) {
            pr += agent_load_f(&slot[4 * i]);
            sp += agent_load_f(&slot[4 * i + 1]);
            float nc = agent_load_f(&slot[4 * i + 2]);
            sn2 += nc * nc;
        }
#pragma unroll
        for (int o = 32; o; o >>= 1) {
            pr += __shfl_xor(pr, o); sp += __shfl_xor(sp, o); sn2 += __shfl_xor(sn2, o);
        }
        if (tid == 0) {
            const float* meta = (const float*)(ws + WS_META);
            double g2 = (double)agent_load_f(&meta[1]);
            double sa = (double)agent_load_f(&meta[2]);
            double count = 8192.0 * 8191.0;
            double nposoff = (double)sn2 - 8192.0;
            double nneg = count - nposoff;
            double sall = g2 - sa;                 // sum_{i != j} s_ij
            double sneg = sall - (double)sp;
            double loss = ((double)pr + 11.0 * nneg - 10.0 * sneg) / count;
            out[0] = (float)loss;
        }
    }
}

extern "C" void kernel_launch(void* const* d_in, const int* in_sizes, int n_in,
                              void* d_out, int out_size, void* d_ws, size_t ws_size,
                              hipStream_t stream) {
    const float* feat = (const float*)d_in[0];
    const int* labels = (const int*)d_in[1];
    float* out = (float*)d_out;
    char* ws = (char*)d_ws;

    k1_normalize_scan<<<NCLS + NBK1, 256, 0, stream>>>(feat, labels, ws);
    k2_classes<<<NCLS + 1, 256, 0, stream>>>(ws, out);
}

// Round 9
// 21.685 us; speedup vs baseline: 2.2952x; 1.0055x over previous
//
#include <hip/hip_runtime.h>
#include <stdint.h>

#define NROWS 8192
#define NDIM 128
#define NCLS 100
#define NBK1 512                    // normalize blocks (16 rows each), blocks 0..511
#define LCAP 512                    // per-class list capacity (n_c ~ 82 +- 9)

typedef short s16x8 __attribute__((ext_vector_type(8)));
typedef float f32x4 __attribute__((ext_vector_type(4)));
typedef __attribute__((address_space(3))) uint32_t lds_u32_t;
typedef __attribute__((address_space(1))) const uint32_t glb_u32_t;

// ws byte offsets
#define WS_FHAT  0u         // 8192*128 bf16 = 2 MB
#define WS_PG    0x200000u  // 512 x 128 f32 partial g (256 KB)
#define WS_PA    0x240000u  // 512 f32 partial anchor sums
#define WS_LIST  0x241000u  // 100 x 512 int class row lists (200 KB)
#define WS_LCNT  0x274000u  // 100 int class counts
#define WS_SLOT  0x275000u  // 100 float4 {prelu, spos, n, pad}
#define WS_META  0x275800u  // [1]=||g||^2, [2]=sum anchors
#define WS_DONE  0x275840u  // k2 election counter

__device__ __forceinline__ uint32_t f32_to_bf16_rne(float x) {
    uint32_t u = __float_as_uint(x);
    return (u + 0x7FFFu + ((u >> 16) & 1u)) >> 16;
}

__device__ __forceinline__ float agent_load_f(const float* p) {
    return __hip_atomic_load(p, __ATOMIC_RELAXED, __HIP_MEMORY_SCOPE_AGENT);
}

// Blocks 0..511: normalize 16 rows each (float4/lane, half-wave per row, both
//   rounds' loads issued up-front) -> fhat (bf16, nontemporal), partial g/anchor.
// Blocks 512..611: build class (b-512)'s row list (independent of normalize).
__global__ __launch_bounds__(256) void k1_normalize_scan(const float* __restrict__ feat,
                                                         const int* __restrict__ labels,
                                                         char* __restrict__ ws) {
    int tid = threadIdx.x;
    int wave = tid >> 6, lane = tid & 63;

    if (blockIdx.x >= NBK1) {
        // ---- list builder for class b ----
        __shared__ int lcnt;
        int b = blockIdx.x - NBK1;
        if (tid == 0) {
            lcnt = 0;
            if (b == 0) *(int*)(ws + WS_DONE) = 0;   // reset k2 election counter
        }
        // int64-label detect: values 0..99 -> all odd int32 words zero
        unsigned long long bl = __ballot(labels[2 * lane + 1] != 0);
        int shl = (bl == 0ull) ? 1 : 0;
        __syncthreads();
        int* list = (int*)(ws + WS_LIST) + b * LCAP;
        int labv[32];
#pragma unroll
        for (int r = 0; r < 32; ++r) labv[r] = labels[(r * 256 + tid) << shl];
#pragma unroll
        for (int r = 0; r < 32; ++r) {
            if (labv[r] == b) {
                int p = atomicAdd(&lcnt, 1);
                if (p < LCAP) list[p] = r * 256 + tid;
            }
        }
        __syncthreads();
        if (tid == 0) ((int*)(ws + WS_LCNT))[b] = lcnt;
        return;
    }

    // ---- normalize 16 rows: 2 rows/wave/round x 2 rounds, loads prefetched ----
    int nb = blockIdx.x;
    const float4* fp4 = (const float4*)feat;
    char* fhatc = ws + WS_FHAT;
    int half = lane >> 5, sl = lane & 31;        // half-wave owns one row
    int r0 = nb * 16 + wave * 2 + half;          // round-0 row
    int r1 = r0 + 8;                             // round-1 row
    float4 v0 = fp4[r0 * 32 + sl];               // independent: both issued together
    float4 v1 = fp4[r1 * 32 + sl];

    float g0 = 0.f, g1 = 0.f, g2 = 0.f, g3 = 0.f, aa = 0.f;
#pragma unroll
    for (int q = 0; q < 2; ++q) {
        float4 v = q ? v1 : v0;
        int row = q ? r1 : r0;
        float ss = v.x * v.x + v.y * v.y + v.z * v.z + v.w * v.w;
#pragma unroll
        for (int o = 16; o; o >>= 1) ss += __shfl_xor(ss, o);   // within 32-lane half
        float sc = 1.0f / fmaxf(sqrtf(ss), 1e-12f);
        float f0 = v.x * sc, f1 = v.y * sc, f2 = v.z * sc, f3 = v.w * sc;
        g0 += f0; g1 += f1; g2 += f2; g3 += f3;
        aa += (sl == 0) ? ss * sc * sc : 0.f;    // ||f_hat||^2, once per row
        uint64_t pk = ((uint64_t)((f32_to_bf16_rne(f3) << 16) | f32_to_bf16_rne(f2)) << 32)
                      | ((f32_to_bf16_rne(f1) << 16) | f32_to_bf16_rne(f0));
        // nontemporal: stream to memory so k2's cross-XCD reads hit clean L3,
        // not a remote dirty L2 line
        __builtin_nontemporal_store(pk, (uint64_t*)(fhatc + row * 256 + sl * 8));
    }

    __shared__ float gbuf[8][128];
    __shared__ float abuf[4];
    *(float4*)&gbuf[wave * 2 + half][sl * 4] = float4{g0, g1, g2, g3};
#pragma unroll
    for (int o = 32; o; o >>= 1) aa += __shfl_xor(aa, o);
    if (lane == 0) abuf[wave] = aa;
    __syncthreads();
    if (tid < NDIM) {
        float s = 0.f;
#pragma unroll
        for (int p = 0; p < 8; ++p) s += gbuf[p][tid];
        ((float*)(ws + WS_PG))[nb * NDIM + tid] = s;
    }
    if (tid == 0) ((float*)(ws + WS_PA))[nb] = abuf[0] + abuf[1] + abuf[2] + abuf[3];
}

// Blocks 0..99: within-class pairwise MFMA (list prebuilt by k1).
// Block 100: reduce partial g -> ||g||^2 and partial anchors -> meta.
// Last-arriving block computes the final loss scalar.
__global__ __launch_bounds__(256) void k2_classes(char* __restrict__ ws,
                                                  float* __restrict__ out) {
    __shared__ __align__(16) char sm[65536];  // A tile [0,32K), B tile [32K,64K)
    __shared__ int win;
    int tid = threadIdx.x;
    int lane = tid & 63, wave = tid >> 6;

    if (blockIdx.x == NCLS) {
        const float* pg = (const float*)(ws + WS_PG);
        const float* pa = (const float*)(ws + WS_PA);
        int dim = tid & 127, half = tid >> 7;
        float acc = 0.f;
#pragma unroll 16
        for (int b = half * 256; b < half * 256 + 256; ++b) acc += pg[b * NDIM + dim];
        float* l = (float*)sm;
        l[half * 128 + dim] = acc;
        float av = pa[tid] + pa[tid + 256];
#pragma unroll
        for (int o = 32; o; o >>= 1) av += __shfl_xor(av, o);
        __syncthreads();
        float sq = 0.f;
        if (half == 0) { float tot = l[dim] + l[128 + dim]; sq = tot * tot; }
#pragma unroll
        for (int o = 32; o; o >>= 1) sq += __shfl_xor(sq, o);
        float* r2 = (float*)sm + 256;
        if (lane == 0) { r2[wave * 2] = sq; r2[wave * 2 + 1] = av; }
        __syncthreads();
        if (tid == 0) {
            float* meta = (float*)(ws + WS_META);
            meta[1] = r2[0] + r2[2] + r2[4] + r2[6];
            meta[2] = r2[1] + r2[3] + r2[5] + r2[7];
        }
    } else {
        int c = blockIdx.x;
        int nfull = ((const int*)(ws + WS_LCNT))[c];
        int n = nfull > LCAP ? LCAP : nfull;
        const int* list = (const int*)(ws + WS_LIST) + c * LCAP;
        const char* fhat = ws + WS_FHAT;
        int wm = wave >> 1, wn = wave & 1;
        float prelu = 0.f, spos = 0.f;
        int ntiles = (n + 127) >> 7;
        int r16 = tid >> 4;
        uint32_t cst = (uint32_t)((tid & 15) << 4);
        for (int ti = 0; ti < ntiles; ++ti)
            for (int tj = 0; tj <= ti; ++tj) {   // symmetric: lower-tri tile pairs only
                int rows_a = n - ti * 128; if (rows_a > 128) rows_a = 128;
                int rows_b = n - tj * 128; if (rows_b > 128) rows_b = 128;
                int slabs_a = (rows_a + 15) >> 4;
                int slabs_b = (rows_b + 15) >> 4;
                bool same = (ti == tj);
                __syncthreads();
                // stage: linear LDS dest, inverse-swizzled per-lane global src
#pragma unroll
                for (int it = 0; it < 8; ++it) {
                    if (it < slabs_a) {
                        int row = it * 16 + r16;
                        uint32_t csrc = cst ^ (uint32_t)((row & 7) << 4);
                        int pa_ = ti * 128 + row;
                        int ra = list[(pa_ < n) ? pa_ : 0];
                        __builtin_amdgcn_global_load_lds(
                            (glb_u32_t*)(fhat + ra * 256 + csrc),
                            (lds_u32_t*)(sm + it * 4096 + tid * 16), 16, 0, 0);
                    }
                }
                if (!same) {
#pragma unroll
                    for (int it = 0; it < 8; ++it) {
                        if (it < slabs_b) {
                            int row = it * 16 + r16;
                            uint32_t csrc = cst ^ (uint32_t)((row & 7) << 4);
                            int pb_ = tj * 128 + row;
                            int rb = list[(pb_ < n) ? pb_ : 0];
                            __builtin_amdgcn_global_load_lds(
                                (glb_u32_t*)(fhat + rb * 256 + csrc),
                                (lds_u32_t*)(sm + 32768 + it * 4096 + tid * 16), 16, 0, 0);
                        }
                    }
                }
                __syncthreads();
                const char* bbase = same ? sm : (sm + 32768);
                int rb_ = lane & 15;
                uint32_t kcol = (uint32_t)((lane >> 4) << 4);
                f32x4 acc[4][4];
#pragma unroll
                for (int mi = 0; mi < 4; ++mi)
#pragma unroll
                    for (int ni = 0; ni < 4; ++ni) acc[mi][ni] = f32x4{0.f, 0.f, 0.f, 0.f};
#pragma unroll
                for (int ks = 0; ks < 4; ++ks) {
                    uint32_t c2 = (uint32_t)(ks * 64) + kcol;
                    s16x8 a[4], bfr[4];
#pragma unroll
                    for (int mi = 0; mi < 4; ++mi) {
                        int r = wm * 64 + mi * 16 + rb_;
                        uint32_t ad = (uint32_t)(r * 256) + (c2 ^ (uint32_t)((r & 7) << 4));
                        a[mi] = *reinterpret_cast<const s16x8*>(sm + ad);
                    }
#pragma unroll
                    for (int ni = 0; ni < 4; ++ni) {
                        int r = wn * 64 + ni * 16 + rb_;
                        uint32_t ad = (uint32_t)(r * 256) + (c2 ^ (uint32_t)((r & 7) << 4));
                        bfr[ni] = *reinterpret_cast<const s16x8*>(bbase + ad);
                    }
#pragma unroll
                    for (int mi = 0; mi < 4; ++mi)
#pragma unroll
                        for (int ni = 0; ni < 4; ++ni)
                            acc[mi][ni] = __builtin_amdgcn_mfma_f32_16x16x32_bf16(
                                a[mi], bfr[ni], acc[mi][ni], 0, 0, 0);
                }
                float tw = same ? 1.f : 2.f;   // off-diagonal tile pairs count twice
#pragma unroll
                for (int ni = 0; ni < 4; ++ni) {
                    int jp = tj * 128 + wn * 64 + ni * 16 + rb_;
#pragma unroll
                    for (int mi = 0; mi < 4; ++mi)
#pragma unroll
                        for (int rr = 0; rr < 4; ++rr) {
                            int ip = ti * 128 + wm * 64 + mi * 16 + ((lane >> 4) << 2) + rr;
                            bool vld = (ip < n) && (jp < n) && (ip != jp);
                            float s = acc[mi][ni][rr];
                            prelu += vld ? tw * fmaxf(fmaf(10.f, s, -9.f), 0.f) : 0.f;
                            spos  += vld ? tw * s : 0.f;
                        }
                }
            }
#pragma unroll
        for (int o = 32; o; o >>= 1) { prelu += __shfl_xor(prelu, o); spos += __shfl_xor(spos, o); }
        __syncthreads();   // tiles dead; reuse sm for the block reduce
        float* rs = (float*)sm;
        if (lane == 0) { rs[wave * 2] = prelu; rs[wave * 2 + 1] = spos; }
        __syncthreads();
        if (tid == 0) {
            float4* slot = (float4*)(ws + WS_SLOT);
            slot[c] = float4{rs[0] + rs[2] + rs[4] + rs[6],
                             rs[1] + rs[3] + rs[5] + rs[7],
                             (float)nfull, 0.f};
        }
    }

    // ---- last-arriving block computes the final scalar ----
    if (tid == 0) {
        __threadfence();
        int old = __hip_atomic_fetch_add((int*)(ws + WS_DONE), 1,
                                         __ATOMIC_ACQ_REL, __HIP_MEMORY_SCOPE_AGENT);
        win = (old == NCLS);  // 101 blocks -> last sees old == 100
    }
    __syncthreads();
    if (win && tid < 64) {
        const float* slot = (const float*)(ws + WS_SLOT);
        float pr = 0.f, sp = 0.f, sn2 = 0.f;
        for (int i = tid; i < NCLS; i += 64) {
            pr += agent_load_f(&slot[4 * i]);
            sp += agent_load_f(&slot[4 * i + 1]);
            float nc = agent_load_f(&slot[4 * i + 2]);
            sn2 += nc * nc;
        }
#pragma unroll
        for (int o = 32; o; o >>= 1) {
            pr += __shfl_xor(pr, o); sp += __shfl_xor(sp, o); sn2 += __shfl_xor(sn2, o);
        }
        if (tid == 0) {
            const float* meta = (const float*)(ws + WS_META);
            double g2 = (double)agent_load_f(&meta[1]);
            double sa = (double)agent_load_f(&meta[2]);
            double count = 8192.0 * 8191.0;
            double nposoff = (double)sn2 - 8192.0;
            double nneg = count - nposoff;
            double sall = g2 - sa;                 // sum_{i != j} s_ij
            double sneg = sall - (double)sp;
            double loss = ((double)pr + 11.0 * nneg - 10.0 * sneg) / count;
            out[0] = (float)loss;
        }
    }
}

extern "C" void kernel_launch(void* const* d_in, const int* in_sizes, int n_in,
                              void* d_out, int out_size, void* d_ws, size_t ws_size,
                              hipStream_t stream) {
    const float* feat = (const float*)d_in[0];
    const int* labels = (const int*)d_in[1];
    float* out = (float*)d_out;
    char* ws = (char*)d_ws;

    k1_normalize_scan<<<NBK1 + NCLS, 256, 0, stream>>>(feat, labels, ws);
    k2_classes<<<NCLS + 1, 256, 0, stream>>>(ws, out);
}